// Round 5
// baseline (405.513 us; speedup 1.0000x reference)
//
#include <hip/hip_runtime.h>
#include <math.h>

#define B_SZ 2
#define H_IN 256
#define W_IN 256
#define HO 128
#define WO 128
#define CIN 128
#define CO_OFF 1152
#define CO_MSK 576
#define NG 64
#define KD 1152           // GEMM K, reordered: k = (kh*3+kw)*128 + ci
#define KBY 2304          // K row bytes in bf16
#define ND 32768          // GEMM N = B*HO*WO
#define MPAD 1792         // 1728 padded to 7*256
#define NTK 18            // K-tiles (1152/64)
#define XTROW_B 66048     // 258*128*2 bytes per padded iy row
#define XTIMG_B 17040384  // 258*XTROW_B bytes per image

typedef short short8 __attribute__((ext_vector_type(8)));
typedef float f32x4 __attribute__((ext_vector_type(4)));
typedef const unsigned int __attribute__((address_space(1))) gcu32;
typedef unsigned int __attribute__((address_space(3))) slu32;

__device__ __forceinline__ unsigned short f2b(float v) {
  union { float f; unsigned u; } a; a.f = v;
  unsigned r = a.u + 0x7FFF + ((a.u >> 16) & 1);
  return (unsigned short)(r >> 16);
}
__device__ __forceinline__ float b2f(unsigned short u) {
  union { unsigned u; float f; } a; a.u = ((unsigned)u) << 16;
  return a.f;
}

// ---------------------------------------------------------------------------
// x (NCHW f32) -> x_t [b][iy+1][ix+1][ci] bf16, zero-padded borders.
// ---------------------------------------------------------------------------
__global__ __launch_bounds__(256) void xpose(const float* __restrict__ x,
                                             unsigned short* __restrict__ xt) {
  const int bid = blockIdx.x;            // 2*258
  const int iyt = bid % 258;
  const int b = bid / 258;
  const int tid = threadIdx.x;
  char* rowp = (char*)xt + (size_t)b * XTIMG_B + (size_t)iyt * XTROW_B;
  const int iy = iyt - 1;
  const short8 z8 = {0, 0, 0, 0, 0, 0, 0, 0};

  if (iy < 0 || iy >= H_IN) {            // full zero row
    for (int i = tid; i < 4128; i += 256)
      *reinterpret_cast<short8*>(rowp + i * 16) = z8;
    return;
  }
  if (tid < 32) {                        // ix = -1 and 256 pad columns
    int c = tid & 15;
    *reinterpret_cast<short8*>(rowp + ((tid >> 4) ? 257 * 256 : 0) + c * 16) = z8;
  }

  __shared__ float sX[32][68];
  const float* xb = x + (size_t)b * CIN * 65536 + iy * 256;
  for (int ci0 = 0; ci0 < CIN; ci0 += 32) {
    for (int ix0 = 0; ix0 < W_IN; ix0 += 64) {
      __syncthreads();
      {
        int ci_l = tid >> 3, f4 = tid & 7;
        const float4* src = reinterpret_cast<const float4*>(
            xb + (size_t)(ci0 + ci_l) * 65536 + ix0);
        *reinterpret_cast<float4*>(&sX[ci_l][f4 * 4]) = src[f4];
        *reinterpret_cast<float4*>(&sX[ci_l][(f4 + 8) * 4]) = src[f4 + 8];
      }
      __syncthreads();
      {
        int ix_l = tid >> 2, cq = (tid & 3) * 8;
        short8 o;
        #pragma unroll
        for (int e = 0; e < 8; e++) o[e] = (short)f2b(sX[cq + e][ix_l]);
        *reinterpret_cast<short8*>(rowp + (ix0 + ix_l + 1) * 256 + (ci0 + cq) * 2) = o;
      }
    }
  }
}

// ---------------------------------------------------------------------------
// Pack weights bf16 [MPAD][KD], K reordered: wb[m][tap*128+ci] = w[m][ci*9+tap]
// ---------------------------------------------------------------------------
__global__ __launch_bounds__(256) void pack_w(const float* __restrict__ w_off,
                                              const float* __restrict__ w_msk,
                                              unsigned short* __restrict__ wb) {
  int i = blockIdx.x * 256 + threadIdx.x;        // MPAD*KD exact
  int m = i / KD;
  int k = i - m * KD;
  int tap = k >> 7, ci = k & 127;
  int src = ci * 9 + tap;
  float v = 0.f;
  if (m < CO_OFF) v = w_off[(size_t)m * KD + src];
  else if (m < 1728) v = w_msk[(size_t)(m - CO_OFF) * KD + src];
  wb[i] = f2b(v);
}

// ---------------------------------------------------------------------------
// 256x256 8-phase MFMA GEMM (T2+T3+T4+T5), implicit-conv B from x_t.
// 8 waves (2M x 4N), per-wave 128x64. buf0 = even K-tiles, buf1 = odd.
// Staging: B-halves of tile t+2 at ph3/ph7, A-halves at ph4/ph8 (regions freed
// exactly one phase earlier). vmcnt(8) at ph4/ph8 covers reads 4 phases later;
// final iteration uses vmcnt(0).
// ---------------------------------------------------------------------------
__global__ __launch_bounds__(512) void gemm_conv(
    const unsigned short* __restrict__ wb, const unsigned short* __restrict__ xt,
    const float* __restrict__ b_off, const float* __restrict__ b_msk,
    unsigned short* __restrict__ offs, unsigned short* __restrict__ mask)
{
  __shared__ __attribute__((aligned(128))) char lds[2][65536];  // [buf][A 32K | B 32K]

  const int bid = blockIdx.x;                    // 896 = 7 m-tiles x 128 n-tiles
  const int swz = (bid & 7) * 112 + (bid >> 3);  // bijective XCD swizzle
  const int m0 = (swz % 7) * 256;
  const int n0 = (swz / 7) * 256;
  const int b  = n0 >> 14;
  const int ho_base = (n0 & 16383) >> 7;         // even, 0..126

  const int tid = threadIdx.x;
  const int l = tid & 63;
  const int w = tid >> 6;

  const int rl = l >> 3;                          // row within 8-row chunk
  const int kbsw = ((l & 7) << 4) ^ (rl << 4);    // inverse-swizzled src k-byte

  // wave w stages A chunks 4w..4w+3 (rows m0+32w+8j+rl) and B chunks 4w..4w+3
  // (n-rows 32w+8j+rl -> ho_l = w>>2, wo = (w&3)*32+8j+rl)
  const char* pA = (const char*)wb + (size_t)(m0 + 32 * w + rl) * KBY + kbsw;
  const char* pB = (const char*)xt + (size_t)b * XTIMG_B
                 + (size_t)(2 * (ho_base + (w >> 2))) * XTROW_B
                 + (2 * ((w & 3) * 32 + rl)) * 256 + kbsw;

  const int fr = l & 15;
  const int kq = (l >> 4) << 4;
  const int wm = (w >> 2) * 128;                  // 2 m-groups of 128
  const int wn = (w & 3) * 64;                    // 4 n-groups of 64

  f32x4 acc[8][4];
  #pragma unroll
  for (int a = 0; a < 8; a++)
    #pragma unroll
    for (int c = 0; c < 4; c++) acc[a][c] = (f32x4)(0.f);

  short8 af[4][2];    // current mi-group (4 mi x 2 kk)
  short8 bfr[4][2];   // all 4 ni x 2 kk

#define STAGE_A(kt, bf) { const char* s_ = pA + (kt) * 128; \
  char* d_ = &lds[bf][0] + w * 4096; \
  _Pragma("unroll") for (int j_ = 0; j_ < 4; j_++) \
    __builtin_amdgcn_global_load_lds((gcu32*)(s_ + (size_t)j_ * 8 * KBY), \
                                     (slu32*)(d_ + j_ * 1024), 16, 0, 0); }

#define STAGE_B(kt, bf) { int tap_ = (kt) >> 1; int kh_ = tap_ / 3; int kw_ = tap_ - 3 * kh_; \
  const char* s_ = pB + kh_ * XTROW_B + kw_ * 256 + ((kt) & 1) * 128; \
  char* d_ = &lds[bf][32768] + w * 4096; \
  _Pragma("unroll") for (int j_ = 0; j_ < 4; j_++) \
    __builtin_amdgcn_global_load_lds((gcu32*)(s_ + j_ * 4096), \
                                     (slu32*)(d_ + j_ * 1024), 16, 0, 0); }

#define LDA(mih, bf) _Pragma("unroll") for (int mi_ = 0; mi_ < 4; mi_++) \
  _Pragma("unroll") for (int kk_ = 0; kk_ < 2; kk_++) { \
    int row_ = wm + ((mih) * 4 + mi_) * 16 + fr; \
    af[mi_][kk_] = *(const short8*)(&lds[bf][0] + row_ * 128 + ((kk_ * 64 + kq) ^ ((row_ & 7) << 4))); }

#define LDB(nih, bf) _Pragma("unroll") for (int ni_ = 0; ni_ < 2; ni_++) \
  _Pragma("unroll") for (int kk_ = 0; kk_ < 2; kk_++) { \
    int row_ = wn + ((nih) * 2 + ni_) * 16 + fr; \
    bfr[(nih) * 2 + ni_][kk_] = *(const short8*)(&lds[bf][32768] + row_ * 128 + ((kk_ * 64 + kq) ^ ((row_ & 7) << 4))); }

#define MMQ(mih, nih) __builtin_amdgcn_s_setprio(1); \
  _Pragma("unroll") for (int mi_ = 0; mi_ < 4; mi_++) \
    _Pragma("unroll") for (int ni_ = 0; ni_ < 2; ni_++) \
      _Pragma("unroll") for (int kk_ = 0; kk_ < 2; kk_++) \
        asm("v_mfma_f32_16x16x32_bf16 %0, %1, %2, %0" \
            : "+v"(acc[(mih) * 4 + mi_][(nih) * 2 + ni_]) \
            : "v"(af[mi_][kk_]), "v"(bfr[(nih) * 2 + ni_][kk_])); \
  __builtin_amdgcn_s_setprio(0);

#define BAR __builtin_amdgcn_s_barrier();
#define WAITVM(n) asm volatile("s_waitcnt vmcnt(" #n ")" ::: "memory");

  // prologue: stage tiles 0 (buf0) and 1 (buf1); wait tile 0 landed (leave 8)
  STAGE_B(0, 0) STAGE_A(0, 0) STAGE_B(1, 1) STAGE_A(1, 1)
  WAITVM(8) BAR

  for (int i = 0; i < 9; i++) {
    const bool st = (i < 8);
    // ---- K-tile 2i (buf0) ----
    // ph1: q0 = (mi0-3, ni0-1)
    LDA(0, 0) LDB(0, 0)
    BAR MMQ(0, 0) BAR
    // ph2: q1 = (mi0-3, ni2-3)
    LDB(1, 0)
    BAR MMQ(0, 1) BAR
    // ph3: q2 = (mi4-7, ni0-1); buf0.B freed -> stage B of tile 2i+2
    LDA(1, 0)
    if (st) { STAGE_B(2 * i + 2, 0) }
    BAR MMQ(1, 0) BAR
    // ph4: q3 = (mi4-7, ni2-3); buf0.A freed -> stage A of tile 2i+2
    if (st) { STAGE_A(2 * i + 2, 0) WAITVM(8) } else { WAITVM(0) }
    BAR MMQ(1, 1) BAR
    // ---- K-tile 2i+1 (buf1) ----
    // ph5
    LDA(0, 1) LDB(0, 1)
    BAR MMQ(0, 0) BAR
    // ph6
    LDB(1, 1)
    BAR MMQ(0, 1) BAR
    // ph7: buf1.B freed -> stage B of tile 2i+3
    LDA(1, 1)
    if (st) { STAGE_B(2 * i + 3, 1) }
    BAR MMQ(1, 0) BAR
    // ph8: buf1.A freed -> stage A of tile 2i+3
    if (st) { STAGE_A(2 * i + 3, 1) WAITVM(8) } else { WAITVM(0) }
    BAR MMQ(1, 1) BAR
  }

  // epilogue: m = m0+wm+mi*16+(l>>4)*4+r, n = n0+wn+ni*16+(l&15)
  const int nl0 = (n0 & 16383) + wn;
  const int rq = (l >> 4) * 4;
  #pragma unroll
  for (int mi = 0; mi < 8; mi++) {
    #pragma unroll
    for (int r = 0; r < 4; r++) {
      int m = m0 + wm + mi * 16 + rq + r;
      if (m < 1728) {
        bool ismk = (m >= CO_OFF);
        float bias = ismk ? b_msk[m - CO_OFF] : b_off[m];
        unsigned short* dst = ismk
            ? mask + (((size_t)(b * CO_MSK + (m - CO_OFF))) << 14)
            : offs + (((size_t)(b * CO_OFF + m)) << 14);
        #pragma unroll
        for (int ni = 0; ni < 4; ni++) {
          float v = acc[mi][ni][r] + bias;
          if (ismk) v = 1.f / (1.f + expf(-v));
          dst[nl0 + ni * 16 + fr] = f2b(v);
        }
      }
    }
  }
}

// ---------------------------------------------------------------------------
// Deformable gather + per-group 2x2x9 einsum (offs/mask bf16). Unchanged.
// ---------------------------------------------------------------------------
__global__ __launch_bounds__(256) void deform(
    const float* __restrict__ x, const unsigned short* __restrict__ offs,
    const unsigned short* __restrict__ mask, const float* __restrict__ wd,
    float* __restrict__ out)
{
  const int bid = blockIdx.x;               // B * G * (HO/2) = 8192
  const int hp = bid & 63;
  const int g  = (bid >> 6) & 63;
  const int b  = bid >> 12;
  const int tid = threadIdx.x;
  const int wo = tid & 127;
  const int ho = hp * 2 + (tid >> 7);

  __shared__ float swd[36];
  if (tid < 36) swd[tid] = wd[g * 36 + tid];
  __syncthreads();

  const float* xg = x + ((size_t)(b * CIN + g * 2)) * (H_IN * W_IN);
  float acc0 = 0.f, acc1 = 0.f;
  const int pbase = ((b * CO_OFF + g * 18) * HO + ho) * WO + wo;
  const int mbase = ((b * CO_MSK + g * 9) * HO + ho) * WO + wo;

  #pragma unroll
  for (int k = 0; k < 9; k++) {
    float dy = b2f(offs[pbase + (2 * k) * (HO * WO)]);
    float dx = b2f(offs[pbase + (2 * k + 1) * (HO * WO)]);
    float m  = b2f(mask[mbase + k * (HO * WO)]);
    float py = dy + (float)(ho * 2 - 1 + k / 3);
    float px = dx + (float)(wo * 2 - 1 + k % 3);
    float y0f = floorf(py), x0f = floorf(px);
    float wy = py - y0f, wx = px - x0f;
    float v0 = 0.f, v1 = 0.f;
    #pragma unroll
    for (int t = 0; t < 4; t++) {
      float yc = y0f + (float)(t >> 1);
      float xc = x0f + (float)(t & 1);
      float wgt = ((t >> 1) ? wy : 1.f - wy) * ((t & 1) ? wx : 1.f - wx);
      if (yc >= 0.f && yc <= (float)(H_IN - 1) && xc >= 0.f && xc <= (float)(W_IN - 1)) {
        int idx = (int)yc * W_IN + (int)xc;
        v0 += wgt * xg[idx];
        v1 += wgt * xg[H_IN * W_IN + idx];
      }
    }
    acc0 += m * (swd[0 * 18 + 0 * 9 + k] * v0 + swd[0 * 18 + 1 * 9 + k] * v1);
    acc1 += m * (swd[1 * 18 + 0 * 9 + k] * v0 + swd[1 * 18 + 1 * 9 + k] * v1);
  }

  out[((size_t)(b * CIN + g * 2 + 0) * HO + ho) * WO + wo] = acc0;
  out[((size_t)(b * CIN + g * 2 + 1) * HO + ho) * WO + wo] = acc1;
}

extern "C" void kernel_launch(void* const* d_in, const int* in_sizes, int n_in,
                              void* d_out, int out_size, void* d_ws, size_t ws_size,
                              hipStream_t stream) {
  const float* x     = (const float*)d_in[0];
  const float* w_off = (const float*)d_in[1];
  const float* b_off = (const float*)d_in[2];
  const float* w_msk = (const float*)d_in[3];
  const float* b_msk = (const float*)d_in[4];
  const float* w_def = (const float*)d_in[5];
  float* out = (float*)d_out;

  unsigned short* xt   = (unsigned short*)d_ws;                 // 34.1 MB
  unsigned short* wbf  = xt + (size_t)B_SZ * 258 * 258 * CIN;   // 4.1 MB
  unsigned short* offs = wbf + (size_t)MPAD * KD;               // 75.5 MB
  unsigned short* mask = offs + (size_t)B_SZ * CO_OFF * HO * WO;// 37.7 MB

  xpose<<<B_SZ * 258, 256, 0, stream>>>(x, xt);
  pack_w<<<(MPAD * KD) / 256, 256, 0, stream>>>(w_off, w_msk, wbf);
  gemm_conv<<<896, 512, 0, stream>>>(wbf, xt, b_off, b_msk, offs, mask);
  deform<<<B_SZ * NG * (HO / 2), 256, 0, stream>>>(x, offs, mask, w_def, out);
}